// Round 8
// baseline (386.639 us; speedup 1.0000x reference)
//
#include <hip/hip_runtime.h>
#include <hip/hip_bf16.h>
#include <math.h>

#define F_IN 256
#define F_OUT 64
#define LRELU_ALPHA 0.2f
#define EPS 1e-15f
#define CHUNK 8192           // edges per partition block
#define BSH 7                // bucket = src >> 7  (128 nodes/bucket)
#define BNODES 128
#define NBMAX 1024           // max coarse buckets (N <= 131072)
#define LCAP 4800            // per-bucket cap (mean 4096, +11 sigma)

typedef __bf16 bf16x8 __attribute__((ext_vector_type(8)));
typedef float  f32x4  __attribute__((ext_vector_type(4)));

__device__ __forceinline__ unsigned int fkey(float x) {
    unsigned int u = __float_as_uint(x);
    return (u & 0x80000000u) ? ~u : (u | 0x80000000u);
}
__device__ __forceinline__ float funkey(unsigned int k) {
    return (k & 0x80000000u) ? __uint_as_float(k ^ 0x80000000u)
                             : __uint_as_float(~k);
}
__device__ __forceinline__ unsigned short f2bf(float x) {
    __hip_bfloat16 b = __float2bfloat16(x);
    return *reinterpret_cast<unsigned short*>(&b);
}
__device__ __forceinline__ float bf2f(unsigned int u) {
    return __uint_as_float(u << 16);
}

// ---------------------------------------------------------------------------
// K0: W prep — W[256][64] fp32 -> Wt[64][256] bf16 (transposed).
// 64 blocks x 256 thr, one element each (was 1 block doing 64 serial iters
// = ~55 us; now ~2 us).
// ---------------------------------------------------------------------------
__global__ __launch_bounds__(256) void wprep(
    const float* __restrict__ W, unsigned short* __restrict__ Wt)
{
    const int i = blockIdx.x * 256 + threadIdx.x;   // 0..16383
    const int n = i & 63;
    const int k = i >> 6;
    Wt[n * 256 + k] = f2bf(W[k * 64 + n]);          // read coalesced in n
}

// ---------------------------------------------------------------------------
// K1: MFMA bf16 GEMM (round-5 verified body, standalone again).
// ---------------------------------------------------------------------------
#define KAP 72
#define KWP 264
__global__ __launch_bounds__(256) void gemm_mfma(
    const float* __restrict__ X, const unsigned short* __restrict__ Wt,
    const float* __restrict__ a,
    unsigned short* __restrict__ h_bf, float* __restrict__ s1,
    float* __restrict__ s2, unsigned int* __restrict__ gsmax, int N)
{
    __shared__ unsigned short As[128 * KAP];   // 18432 B
    __shared__ unsigned short Ws[64 * KWP];    // 33792 B
    __shared__ float red1[4], red2[4];

    const int tid  = threadIdx.x;
    const int lane = tid & 63;
    const int l15  = lane & 15;
    const int quad = lane >> 4;
    const int w    = tid >> 6;
    const int n0   = blockIdx.x * 128;

#pragma unroll
    for (int i = 0; i < 16; ++i) {
        int q  = tid + i * 256;
        int n  = q >> 6;
        int k4 = q & 63;
        *(uint2*)&Ws[n * KWP + k4 * 4] = *(const uint2*)&Wt[n * 256 + k4 * 4];
    }

    f32x4 acc[2][4] = {};

    for (int c = 0; c < 4; ++c) {
        __syncthreads();
#pragma unroll
        for (int i = 0; i < 8; ++i) {
            int q   = tid + i * 256;
            int row = q >> 4;
            int k4  = q & 15;
            int gr  = n0 + row;
            float4 v = make_float4(0.f, 0.f, 0.f, 0.f);
            if (gr < N)
                v = *(const float4*)&X[(size_t)gr * F_IN + c * 64 + k4 * 4];
            unsigned int p0 = f2bf(v.x) | ((unsigned int)f2bf(v.y) << 16);
            unsigned int p1 = f2bf(v.z) | ((unsigned int)f2bf(v.w) << 16);
            *(uint2*)&As[row * KAP + k4 * 4] = make_uint2(p0, p1);
        }
        __syncthreads();

#pragma unroll
        for (int ks = 0; ks < 64; ks += 32) {
            bf16x8 afrag[2], bfrag[4];
#pragma unroll
            for (int rt = 0; rt < 2; ++rt) {
                uint4 ua = *(const uint4*)&As[(w * 32 + rt * 16 + l15) * KAP + ks + quad * 8];
                afrag[rt] = __builtin_bit_cast(bf16x8, ua);
            }
#pragma unroll
            for (int ct = 0; ct < 4; ++ct) {
                uint4 ub = *(const uint4*)&Ws[(ct * 16 + l15) * KWP + c * 64 + ks + quad * 8];
                bfrag[ct] = __builtin_bit_cast(bf16x8, ub);
            }
#pragma unroll
            for (int rt = 0; rt < 2; ++rt)
#pragma unroll
                for (int ct = 0; ct < 4; ++ct)
                    acc[rt][ct] = __builtin_amdgcn_mfma_f32_16x16x32_bf16(
                        afrag[rt], bfrag[ct], acc[rt][ct], 0, 0, 0);
        }
    }

    float a1v[4], a2v[4];
#pragma unroll
    for (int ct = 0; ct < 4; ++ct) {
        a1v[ct] = a[ct * 16 + l15];
        a2v[ct] = a[F_OUT + ct * 16 + l15];
    }
    float m1 = -INFINITY, m2 = -INFINITY;
#pragma unroll
    for (int rt = 0; rt < 2; ++rt) {
#pragma unroll
        for (int reg = 0; reg < 4; ++reg) {
            int n = n0 + w * 32 + rt * 16 + quad * 4 + reg;
            float p1 = 0.f, p2 = 0.f;
#pragma unroll
            for (int ct = 0; ct < 4; ++ct) {
                float v = acc[rt][ct][reg];
                p1 = fmaf(v, a1v[ct], p1);
                p2 = fmaf(v, a2v[ct], p2);
            }
#pragma unroll
            for (int ofs = 1; ofs < 16; ofs <<= 1) {
                p1 += __shfl_xor(p1, ofs, 64);
                p2 += __shfl_xor(p2, ofs, 64);
            }
            if (n < N) {
#pragma unroll
                for (int ct = 0; ct < 4; ++ct)
                    h_bf[(size_t)n * F_OUT + ct * 16 + l15] = f2bf(acc[rt][ct][reg]);
                if (l15 == 0) { s1[n] = p1; s2[n] = p2; }
                m1 = fmaxf(m1, p1);
                m2 = fmaxf(m2, p2);
            }
        }
    }
#pragma unroll
    for (int ofs = 32; ofs > 0; ofs >>= 1) {
        m1 = fmaxf(m1, __shfl_xor(m1, ofs, 64));
        m2 = fmaxf(m2, __shfl_xor(m2, ofs, 64));
    }
    if (lane == 0) { red1[w] = m1; red2[w] = m2; }
    __syncthreads();
    if (tid == 0) {
        float b1 = fmaxf(fmaxf(red1[0], red1[1]), fmaxf(red1[2], red1[3]));
        float b2 = fmaxf(fmaxf(red2[0], red2[1]), fmaxf(red2[2], red2[3]));
        atomicMax(&gsmax[0], fkey(b1));
        atomicMax(&gsmax[1], fkey(b2));
    }
}

// ---------------------------------------------------------------------------
// K2: coarse partition (standalone again — 8 KB LDS -> full occupancy).
// 128-node buckets; packed (dst<<7 | src&127) appended to moving fronts.
// ---------------------------------------------------------------------------
__global__ __launch_bounds__(256) void partition_edges(
    const int* __restrict__ src, const int* __restrict__ dst,
    int* __restrict__ coarse_cnt, unsigned int* __restrict__ coarse,
    int E, int NB)
{
    __shared__ int hist[NBMAX];
    __shared__ int cur[NBMAX];
    const int e0 = blockIdx.x * CHUNK;
    const int e1 = (e0 + CHUNK < E) ? e0 + CHUNK : E;

    for (int i = threadIdx.x; i < NB; i += 256) hist[i] = 0;
    __syncthreads();
    for (int e = e0 + threadIdx.x; e < e1; e += 256)
        atomicAdd(&hist[src[e] >> BSH], 1);
    __syncthreads();
    for (int i = threadIdx.x; i < NB; i += 256) {
        int c = hist[i];
        cur[i] = c ? atomicAdd(&coarse_cnt[i], c) : 0;
    }
    __syncthreads();
    for (int e = e0 + threadIdx.x; e < e1; e += 256) {
        int s = src[e], d = dst[e];
        int b = s >> BSH;
        int pos = atomicAdd(&cur[b], 1);
        if (pos < LCAP)
            coarse[(size_t)b * LCAP + pos] =
                ((unsigned int)d << BSH) | (unsigned int)(s & (BNODES - 1));
    }
}

// ---------------------------------------------------------------------------
// K3: merged fine-bin + gather, 512 threads per 128-node bucket.
// A: LDS histogram.  B: LDS scan.  C: w = exp(lrelu(s1+s2)-M), scatter
// (dst<<15 | bf16(w)) into LDS CSR.
// D: one node per WAVE; lanes in 4 groups of 16; group g takes edge k+g via
// one shfl; each lane loads uint2 = 4 bf16 features (512 B per wave-instr,
// 4 edges per step); 4 fmas into per-lane accums; cross-group reduce at node
// end (2 shfl_xor per accum). ~2.5 wave-instr per edge.
// ---------------------------------------------------------------------------
__global__ __launch_bounds__(512) void bin_gather(
    const unsigned int* __restrict__ coarse, const int* __restrict__ coarse_cnt,
    const float* __restrict__ s1, const float* __restrict__ s2,
    const unsigned int* __restrict__ gsmax,
    const unsigned short* __restrict__ hb, float* __restrict__ out, int N)
{
    __shared__ unsigned int leds[LCAP];      // 19200 B
    __shared__ int   hcnt[BNODES];
    __shared__ int   hinc[BNODES];
    __shared__ int   curs[BNODES];
    __shared__ float s1s[BNODES];

    const int b  = blockIdx.x;
    const int t  = threadIdx.x;
    const int n0 = b << BSH;
    int cnt = coarse_cnt[b];
    if (cnt > LCAP) cnt = LCAP;
    const unsigned int* cb = coarse + (size_t)b * LCAP;

    if (t < BNODES) {
        hcnt[t] = 0;
        s1s[t] = (n0 + t < N) ? s1[n0 + t] : 0.f;
    }
    __syncthreads();

    // Phase A: histogram of local src
    for (int e = t; e < cnt; e += 512)
        atomicAdd(&hcnt[cb[e] & (BNODES - 1)], 1);
    __syncthreads();

    // Phase B: inclusive scan over BNODES counters
    if (t < BNODES) hinc[t] = hcnt[t];
    __syncthreads();
    for (int d = 1; d < BNODES; d <<= 1) {
        int x = (t < BNODES && t >= d) ? hinc[t - d] : 0;
        __syncthreads();
        if (t < BNODES) hinc[t] += x;
        __syncthreads();
    }
    if (t < BNODES) curs[t] = hinc[t] - hcnt[t];
    __syncthreads();

    // Phase C: weights + LDS scatter
    const float M = funkey(gsmax[0]) + funkey(gsmax[1]);
    for (int e = t; e < cnt; e += 512) {
        unsigned int p = cb[e];
        int sl = p & (BNODES - 1);
        int d  = p >> BSH;
        float v = s1s[sl] + s2[d];
        v = fmaxf(v, LRELU_ALPHA * v);          // leaky-relu
        float w = __expf(v - M);                // in (0,1]
        unsigned int wb = f2bf(w);              // sign=0 -> 15 bits
        int pos = atomicAdd(&curs[sl], 1);
        leds[pos] = ((unsigned int)d << 15) | wb;
    }
    __syncthreads();

    // Phase D: gather. Wave wv handles nodes [wv*16, wv*16+16).
    const int lane = t & 63;
    const int wv   = t >> 6;                 // 0..7
    const int g    = lane >> 4;              // edge-group 0..3
    const int fi   = lane & 15;              // feature-quad index

    for (int i = 0; i < 16; ++i) {
        const int nl = wv * 16 + i;
        const int n  = n0 + nl;
        const bool valid = (n < N);
        const int re = valid ? hinc[nl] : 0;
        const int rs = valid ? re - hcnt[nl] : 0;

        float a0 = 0.f, a1 = 0.f, a2 = 0.f, a3 = 0.f, ws = 0.f;
        for (int bb = rs; bb < re; bb += 64) {
            const int nb = (re - bb < 64) ? re - bb : 64;
            unsigned int pv = (lane < nb) ? leds[bb + lane] : 0u;
            ws += bf2f(pv & 0x7fffu);
            for (int k = 0; k < nb; k += 4) {
                unsigned int pe = __shfl(pv, k + g, 64);   // idx <= 63 (pv=0 pad)
                float w = bf2f(pe & 0x7fffu);
                uint2 hv = *(const uint2*)&hb[(size_t)(pe >> 15) * F_OUT + fi * 4];
                a0 = fmaf(w, bf2f(hv.x & 0xffffu), a0);
                a1 = fmaf(w, bf2f(hv.x >> 16),     a1);
                a2 = fmaf(w, bf2f(hv.y & 0xffffu), a2);
                a3 = fmaf(w, bf2f(hv.y >> 16),     a3);
            }
        }
        // cross-group accumulator reduce (groups differ in lane bits 4-5)
        a0 += __shfl_xor(a0, 16, 64); a0 += __shfl_xor(a0, 32, 64);
        a1 += __shfl_xor(a1, 16, 64); a1 += __shfl_xor(a1, 32, 64);
        a2 += __shfl_xor(a2, 16, 64); a2 += __shfl_xor(a2, 32, 64);
        a3 += __shfl_xor(a3, 16, 64); a3 += __shfl_xor(a3, 32, 64);
        // full weight-sum reduce
#pragma unroll
        for (int ofs = 32; ofs > 0; ofs >>= 1)
            ws += __shfl_xor(ws, ofs, 64);

        if (valid && g == 0) {
            float inv = 1.f / (ws + EPS);
            float x0 = a0 * inv, x1 = a1 * inv, x2 = a2 * inv, x3 = a3 * inv;
            x0 = (x0 > 0.f) ? x0 : expm1f(x0);
            x1 = (x1 > 0.f) ? x1 : expm1f(x1);
            x2 = (x2 > 0.f) ? x2 : expm1f(x2);
            x3 = (x3 > 0.f) ? x3 : expm1f(x3);
            *(float4*)&out[(size_t)n * F_OUT + fi * 4] = make_float4(x0, x1, x2, x3);
        }
    }
}

extern "C" void kernel_launch(void* const* d_in, const int* in_sizes, int n_in,
                              void* d_out, int out_size, void* d_ws, size_t ws_size,
                              hipStream_t stream) {
    const float* X   = (const float*)d_in[0];
    const int*   ei  = (const int*)d_in[1];
    const float* W   = (const float*)d_in[2];
    const float* a   = (const float*)d_in[3];
    float*       out = (float*)d_out;

    const int N = in_sizes[0] / F_IN;     // 100000
    const int E = in_sizes[1] / 2;        // 3200000
    const int* src = ei;
    const int* dst = ei + E;

    const int NB = (N + BNODES - 1) >> BSH;          // 782 buckets
    const int GB = (N + 127) / 128;                  // 782 gemm blocks
    const int PB = (E + CHUNK - 1) / CHUNK;          // 391 partition blocks

    // workspace layout (~29 MB)
    unsigned short* h_bf = (unsigned short*)d_ws;            // N*64 bf16
    float* s1         = (float*)(h_bf + (size_t)N * F_OUT);  // N
    float* s2         = s1 + N;                              // N
    int*   coarse_cnt = (int*)(s2 + N);                      // NB
    unsigned int* gsmax = (unsigned int*)(coarse_cnt + NB);  // 2 (contiguous)
    unsigned short* Wt = (unsigned short*)(gsmax + 2);       // 64*256 bf16
    unsigned int* coarse = (unsigned int*)(Wt + 64 * 256);   // NB*LCAP

    // zero coarse_cnt + gsmax in one memset
    hipMemsetAsync(coarse_cnt, 0, ((size_t)NB + 2) * sizeof(int), stream);

    wprep          <<<64, 256, 0, stream>>>(W, Wt);
    gemm_mfma      <<<GB, 256, 0, stream>>>(X, Wt, a, h_bf, s1, s2, gsmax, N);
    partition_edges<<<PB, 256, 0, stream>>>(src, dst, coarse_cnt, coarse, E, NB);
    bin_gather     <<<NB, 512, 0, stream>>>(coarse, coarse_cnt, s1, s2, gsmax,
                                            h_bf, out, N);
}

// Round 9
// 366.175 us; speedup vs baseline: 1.0559x; 1.0559x over previous
//
#include <hip/hip_runtime.h>
#include <hip/hip_bf16.h>
#include <math.h>

#define F_IN 256
#define F_OUT 64
#define LRELU_ALPHA 0.2f
#define EPS 1e-15f
#define CHUNK 8192           // edges per partition block
#define BSH 7                // bucket = src >> 7  (128 nodes/bucket)
#define BNODES 128
#define NBMAX 1024           // max coarse buckets (N <= 131072)
#define LCAP 4800            // per-bucket cap (mean 4096, +11 sigma)

typedef __bf16 bf16x8 __attribute__((ext_vector_type(8)));
typedef float  f32x4  __attribute__((ext_vector_type(4)));

__device__ __forceinline__ unsigned int fkey(float x) {
    unsigned int u = __float_as_uint(x);
    return (u & 0x80000000u) ? ~u : (u | 0x80000000u);
}
__device__ __forceinline__ float funkey(unsigned int k) {
    return (k & 0x80000000u) ? __uint_as_float(k ^ 0x80000000u)
                             : __uint_as_float(~k);
}
__device__ __forceinline__ unsigned short f2bf(float x) {
    __hip_bfloat16 b = __float2bfloat16(x);
    return *reinterpret_cast<unsigned short*>(&b);
}
__device__ __forceinline__ float bf2f(unsigned int u) {
    return __uint_as_float(u << 16);
}

// ---------------------------------------------------------------------------
// K0: W prep — W[256][64] fp32 -> Wt[64][256] bf16 (transposed). 64 blocks.
// ---------------------------------------------------------------------------
__global__ __launch_bounds__(256) void wprep(
    const float* __restrict__ W, unsigned short* __restrict__ Wt)
{
    const int i = blockIdx.x * 256 + threadIdx.x;   // 0..16383
    const int n = i & 63;
    const int k = i >> 6;
    Wt[n * 256 + k] = f2bf(W[k * 64 + n]);
}

// ---------------------------------------------------------------------------
// K1: FUSED gemm + partition, grid-concat. Union LDS is only 18.5 KB
// (gemm's As tile; Ws eliminated — B-fragments are loaded straight from
// global Wt, which is 32 KB and L2-resident on every XCD), so BOTH branches
// run at 8 blocks/CU and all 1173 blocks are co-resident -> true overlap.
// ---------------------------------------------------------------------------
#define KAP 72
__global__ __launch_bounds__(256) void gemm_part(
    const float* __restrict__ X, const unsigned short* __restrict__ Wt,
    const float* __restrict__ a,
    unsigned short* __restrict__ h_bf, float* __restrict__ s1,
    float* __restrict__ s2, unsigned int* __restrict__ gsmax, int N,
    const int* __restrict__ src, const int* __restrict__ dst,
    int* __restrict__ coarse_cnt, unsigned int* __restrict__ coarse,
    int E, int NB, int GB)
{
    __shared__ __align__(16) char smem[18464];

    if (blockIdx.x < GB) {
        // ---------------- GEMM branch (18.5 KB LDS) ----------------
        unsigned short* As = (unsigned short*)smem;        // 128*KAP*2 = 18432
        float* red1 = (float*)(smem + 18432);              // 4
        float* red2 = red1 + 4;                            // 4

        const int tid  = threadIdx.x;
        const int lane = tid & 63;
        const int l15  = lane & 15;
        const int quad = lane >> 4;
        const int w    = tid >> 6;
        const int n0   = blockIdx.x * 128;

        // per-lane base into Wt for B-fragment loads (ushort units)
        const unsigned short* wbase = Wt + l15 * 256 + quad * 8;

        f32x4 acc[2][4] = {};

        for (int c = 0; c < 4; ++c) {
            __syncthreads();
#pragma unroll
            for (int i = 0; i < 8; ++i) {
                int q   = tid + i * 256;
                int row = q >> 4;
                int k4  = q & 15;
                int gr  = n0 + row;
                float4 v = make_float4(0.f, 0.f, 0.f, 0.f);
                if (gr < N)
                    v = *(const float4*)&X[(size_t)gr * F_IN + c * 64 + k4 * 4];
                unsigned int p0 = f2bf(v.x) | ((unsigned int)f2bf(v.y) << 16);
                unsigned int p1 = f2bf(v.z) | ((unsigned int)f2bf(v.w) << 16);
                *(uint2*)&As[row * KAP + k4 * 4] = make_uint2(p0, p1);
            }
            __syncthreads();

#pragma unroll
            for (int ks = 0; ks < 64; ks += 32) {
                bf16x8 afrag[2], bfrag[4];
#pragma unroll
                for (int rt = 0; rt < 2; ++rt) {
                    uint4 ua = *(const uint4*)&As[(w * 32 + rt * 16 + l15) * KAP + ks + quad * 8];
                    afrag[rt] = __builtin_bit_cast(bf16x8, ua);
                }
#pragma unroll
                for (int ct = 0; ct < 4; ++ct) {
                    uint4 ub = *(const uint4*)&wbase[ct * 4096 + c * 64 + ks];
                    bfrag[ct] = __builtin_bit_cast(bf16x8, ub);
                }
#pragma unroll
                for (int rt = 0; rt < 2; ++rt)
#pragma unroll
                    for (int ct = 0; ct < 4; ++ct)
                        acc[rt][ct] = __builtin_amdgcn_mfma_f32_16x16x32_bf16(
                            afrag[rt], bfrag[ct], acc[rt][ct], 0, 0, 0);
            }
        }

        float a1v[4], a2v[4];
#pragma unroll
        for (int ct = 0; ct < 4; ++ct) {
            a1v[ct] = a[ct * 16 + l15];
            a2v[ct] = a[F_OUT + ct * 16 + l15];
        }
        float m1 = -INFINITY, m2 = -INFINITY;
#pragma unroll
        for (int rt = 0; rt < 2; ++rt) {
#pragma unroll
            for (int reg = 0; reg < 4; ++reg) {
                int n = n0 + w * 32 + rt * 16 + quad * 4 + reg;
                float p1 = 0.f, p2 = 0.f;
#pragma unroll
                for (int ct = 0; ct < 4; ++ct) {
                    float v = acc[rt][ct][reg];
                    p1 = fmaf(v, a1v[ct], p1);
                    p2 = fmaf(v, a2v[ct], p2);
                }
#pragma unroll
                for (int ofs = 1; ofs < 16; ofs <<= 1) {
                    p1 += __shfl_xor(p1, ofs, 64);
                    p2 += __shfl_xor(p2, ofs, 64);
                }
                if (n < N) {
#pragma unroll
                    for (int ct = 0; ct < 4; ++ct)
                        h_bf[(size_t)n * F_OUT + ct * 16 + l15] = f2bf(acc[rt][ct][reg]);
                    if (l15 == 0) { s1[n] = p1; s2[n] = p2; }
                    m1 = fmaxf(m1, p1);
                    m2 = fmaxf(m2, p2);
                }
            }
        }
#pragma unroll
        for (int ofs = 32; ofs > 0; ofs >>= 1) {
            m1 = fmaxf(m1, __shfl_xor(m1, ofs, 64));
            m2 = fmaxf(m2, __shfl_xor(m2, ofs, 64));
        }
        if (lane == 0) { red1[w] = m1; red2[w] = m2; }
        __syncthreads();
        if (tid == 0) {
            float b1 = fmaxf(fmaxf(red1[0], red1[1]), fmaxf(red1[2], red1[3]));
            float b2 = fmaxf(fmaxf(red2[0], red2[1]), fmaxf(red2[2], red2[3]));
            atomicMax(&gsmax[0], fkey(b1));
            atomicMax(&gsmax[1], fkey(b2));
        }
    } else {
        // ---------------- partition branch (8.2 KB of the union) ----------
        int* hist = (int*)smem;          // NBMAX
        int* cur  = hist + NBMAX;        // NBMAX
        const int pb = blockIdx.x - GB;
        const int e0 = pb * CHUNK;
        const int e1 = (e0 + CHUNK < E) ? e0 + CHUNK : E;

        for (int i = threadIdx.x; i < NB; i += 256) hist[i] = 0;
        __syncthreads();
        for (int e = e0 + threadIdx.x; e < e1; e += 256)
            atomicAdd(&hist[src[e] >> BSH], 1);
        __syncthreads();
        for (int i = threadIdx.x; i < NB; i += 256) {
            int c = hist[i];
            cur[i] = c ? atomicAdd(&coarse_cnt[i], c) : 0;
        }
        __syncthreads();
        for (int e = e0 + threadIdx.x; e < e1; e += 256) {
            int s = src[e], d = dst[e];
            int b = s >> BSH;
            int pos = atomicAdd(&cur[b], 1);
            if (pos < LCAP)
                coarse[(size_t)b * LCAP + pos] =
                    ((unsigned int)d << BSH) | (unsigned int)(s & (BNODES - 1));
        }
    }
}

// ---------------------------------------------------------------------------
// K2: merged fine-bin + gather (unchanged from round 8 — 99 us, verified).
// ---------------------------------------------------------------------------
__global__ __launch_bounds__(512) void bin_gather(
    const unsigned int* __restrict__ coarse, const int* __restrict__ coarse_cnt,
    const float* __restrict__ s1, const float* __restrict__ s2,
    const unsigned int* __restrict__ gsmax,
    const unsigned short* __restrict__ hb, float* __restrict__ out, int N)
{
    __shared__ unsigned int leds[LCAP];      // 19200 B
    __shared__ int   hcnt[BNODES];
    __shared__ int   hinc[BNODES];
    __shared__ int   curs[BNODES];
    __shared__ float s1s[BNODES];

    const int b  = blockIdx.x;
    const int t  = threadIdx.x;
    const int n0 = b << BSH;
    int cnt = coarse_cnt[b];
    if (cnt > LCAP) cnt = LCAP;
    const unsigned int* cb = coarse + (size_t)b * LCAP;

    if (t < BNODES) {
        hcnt[t] = 0;
        s1s[t] = (n0 + t < N) ? s1[n0 + t] : 0.f;
    }
    __syncthreads();

    for (int e = t; e < cnt; e += 512)
        atomicAdd(&hcnt[cb[e] & (BNODES - 1)], 1);
    __syncthreads();

    if (t < BNODES) hinc[t] = hcnt[t];
    __syncthreads();
    for (int d = 1; d < BNODES; d <<= 1) {
        int x = (t < BNODES && t >= d) ? hinc[t - d] : 0;
        __syncthreads();
        if (t < BNODES) hinc[t] += x;
        __syncthreads();
    }
    if (t < BNODES) curs[t] = hinc[t] - hcnt[t];
    __syncthreads();

    const float M = funkey(gsmax[0]) + funkey(gsmax[1]);
    for (int e = t; e < cnt; e += 512) {
        unsigned int p = cb[e];
        int sl = p & (BNODES - 1);
        int d  = p >> BSH;
        float v = s1s[sl] + s2[d];
        v = fmaxf(v, LRELU_ALPHA * v);
        float w = __expf(v - M);
        unsigned int wb = f2bf(w);
        int pos = atomicAdd(&curs[sl], 1);
        leds[pos] = ((unsigned int)d << 15) | wb;
    }
    __syncthreads();

    const int lane = t & 63;
    const int wv   = t >> 6;
    const int g    = lane >> 4;
    const int fi   = lane & 15;

    for (int i = 0; i < 16; ++i) {
        const int nl = wv * 16 + i;
        const int n  = n0 + nl;
        const bool valid = (n < N);
        const int re = valid ? hinc[nl] : 0;
        const int rs = valid ? re - hcnt[nl] : 0;

        float a0 = 0.f, a1 = 0.f, a2 = 0.f, a3 = 0.f, ws = 0.f;
        for (int bb = rs; bb < re; bb += 64) {
            const int nb = (re - bb < 64) ? re - bb : 64;
            unsigned int pv = (lane < nb) ? leds[bb + lane] : 0u;
            ws += bf2f(pv & 0x7fffu);
            for (int k = 0; k < nb; k += 4) {
                unsigned int pe = __shfl(pv, k + g, 64);
                float w = bf2f(pe & 0x7fffu);
                uint2 hv = *(const uint2*)&hb[(size_t)(pe >> 15) * F_OUT + fi * 4];
                a0 = fmaf(w, bf2f(hv.x & 0xffffu), a0);
                a1 = fmaf(w, bf2f(hv.x >> 16),     a1);
                a2 = fmaf(w, bf2f(hv.y & 0xffffu), a2);
                a3 = fmaf(w, bf2f(hv.y >> 16),     a3);
            }
        }
        a0 += __shfl_xor(a0, 16, 64); a0 += __shfl_xor(a0, 32, 64);
        a1 += __shfl_xor(a1, 16, 64); a1 += __shfl_xor(a1, 32, 64);
        a2 += __shfl_xor(a2, 16, 64); a2 += __shfl_xor(a2, 32, 64);
        a3 += __shfl_xor(a3, 16, 64); a3 += __shfl_xor(a3, 32, 64);
#pragma unroll
        for (int ofs = 32; ofs > 0; ofs >>= 1)
            ws += __shfl_xor(ws, ofs, 64);

        if (valid && g == 0) {
            float inv = 1.f / (ws + EPS);
            float x0 = a0 * inv, x1 = a1 * inv, x2 = a2 * inv, x3 = a3 * inv;
            x0 = (x0 > 0.f) ? x0 : expm1f(x0);
            x1 = (x1 > 0.f) ? x1 : expm1f(x1);
            x2 = (x2 > 0.f) ? x2 : expm1f(x2);
            x3 = (x3 > 0.f) ? x3 : expm1f(x3);
            *(float4*)&out[(size_t)n * F_OUT + fi * 4] = make_float4(x0, x1, x2, x3);
        }
    }
}

extern "C" void kernel_launch(void* const* d_in, const int* in_sizes, int n_in,
                              void* d_out, int out_size, void* d_ws, size_t ws_size,
                              hipStream_t stream) {
    const float* X   = (const float*)d_in[0];
    const int*   ei  = (const int*)d_in[1];
    const float* W   = (const float*)d_in[2];
    const float* a   = (const float*)d_in[3];
    float*       out = (float*)d_out;

    const int N = in_sizes[0] / F_IN;     // 100000
    const int E = in_sizes[1] / 2;        // 3200000
    const int* src = ei;
    const int* dst = ei + E;

    const int NB = (N + BNODES - 1) >> BSH;          // 782 buckets
    const int GB = (N + 127) / 128;                  // 782 gemm blocks
    const int PB = (E + CHUNK - 1) / CHUNK;          // 391 partition blocks

    // workspace layout (~29 MB)
    unsigned short* h_bf = (unsigned short*)d_ws;            // N*64 bf16
    float* s1         = (float*)(h_bf + (size_t)N * F_OUT);  // N
    float* s2         = s1 + N;                              // N
    int*   coarse_cnt = (int*)(s2 + N);                      // NB
    unsigned int* gsmax = (unsigned int*)(coarse_cnt + NB);  // 2 (contiguous)
    unsigned short* Wt = (unsigned short*)(gsmax + 2);       // 64*256 bf16
    unsigned int* coarse = (unsigned int*)(Wt + 64 * 256);   // NB*LCAP

    hipMemsetAsync(coarse_cnt, 0, ((size_t)NB + 2) * sizeof(int), stream);

    wprep     <<<64, 256, 0, stream>>>(W, Wt);
    gemm_part <<<GB + PB, 256, 0, stream>>>(X, Wt, a, h_bf, s1, s2, gsmax, N,
                                            src, dst, coarse_cnt, coarse,
                                            E, NB, GB);
    bin_gather<<<NB, 512, 0, stream>>>(coarse, coarse_cnt, s1, s2, gsmax,
                                       h_bf, out, N);
}